// Round 11
// baseline (238.535 us; speedup 1.0000x reference)
//
#include <hip/hip_runtime.h>
#include <hip/hip_bf16.h>
#include <math.h>

#define S_LEN 2048
#define B_SZ  4
#define E_DIM 512
#define H_NUM 8
#define HD    64
#define FF_DIM 2048
#define NROWS 8192
#define WIN   128

typedef unsigned short u16;
typedef __bf16 bf16x8 __attribute__((ext_vector_type(8)));
typedef float  f32x4  __attribute__((ext_vector_type(4)));

// fp32 -> bf16 round-to-nearest-even
__device__ __forceinline__ u16 f2bf(float f) {
  union { float f; unsigned u; } v; v.f = f;
  unsigned u = v.u;
  return (u16)((u + 0x7fffu + ((u >> 16) & 1u)) >> 16);
}

// pack two f32 -> u32 of 2 bf16 (RNE), single VALU op
__device__ __forceinline__ unsigned cvtpk(float lo, float hi) {
  unsigned r;
  asm("v_cvt_pk_bf16_f32 %0, %1, %2" : "=v"(r) : "v"(lo), "v"(hi));
  return r;
}

// async global->LDS, 16B per lane; LDS dest = wave-uniform base + lane*16
__device__ __forceinline__ void gl_lds16(const u16* gp, u16* lp) {
  __builtin_amdgcn_global_load_lds(
      (const __attribute__((address_space(1))) unsigned int*)gp,
      (__attribute__((address_space(3))) unsigned int*)lp, 16, 0, 0);
}

// ---------------------------------------------------------------------------
// merged prep: x+pos (first 1048576 float4s) and 4-matrix weight cast
// ---------------------------------------------------------------------------
__global__ __launch_bounds__(256) void prep_kernel(
    const float* __restrict__ x, const float* __restrict__ pos,
    float* __restrict__ xp, u16* __restrict__ xpb,
    const float* __restrict__ s0, const float* __restrict__ s1,
    const float* __restrict__ s2, const float* __restrict__ s3,
    u16* __restrict__ d0, u16* __restrict__ d1,
    u16* __restrict__ d2, u16* __restrict__ d3) {
  int i = blockIdx.x * blockDim.x + threadIdx.x;
  if (i < 1048576) {
    float4 xv = ((const float4*)x)[i];
    float4 pv = ((const float4*)pos)[i & 511];
    float4 o;
    o.x = xv.x + pv.x; o.y = xv.y + pv.y; o.z = xv.z + pv.z; o.w = xv.w + pv.w;
    ((float4*)xp)[i] = o;
    ushort4 ob; ob.x = f2bf(o.x); ob.y = f2bf(o.y); ob.z = f2bf(o.z); ob.w = f2bf(o.w);
    ((ushort4*)xpb)[i] = ob;
  } else {
    int j = i - 1048576;
    const int n0 = 196608, n1 = 65536, n2 = 262144;
    const float4* sp; ushort4* dp; int off;
    if (j < n0)                { sp = (const float4*)s0; dp = (ushort4*)d0; off = j; }
    else if (j < n0 + n1)      { sp = (const float4*)s1; dp = (ushort4*)d1; off = j - n0; }
    else if (j < n0 + n1 + n2) { sp = (const float4*)s2; dp = (ushort4*)d2; off = j - n0 - n1; }
    else                       { sp = (const float4*)s3; dp = (ushort4*)d3; off = j - n0 - n1 - n2; }
    float4 v = sp[off];
    ushort4 o; o.x = f2bf(v.x); o.y = f2bf(v.y); o.z = f2bf(v.z); o.w = f2bf(v.w);
    dp[off] = o;
  }
}

// ---------------------------------------------------------------------------
// bf16 MFMA GEMM (R10-verified; DEPTH=2 and DEPTH=3 paths unchanged)
// ---------------------------------------------------------------------------
#define GBK 64

template <int BN, int GY, int DEPTH>
__global__ __launch_bounds__(256) void mfma_gemm(
    const u16* __restrict__ A, const u16* __restrict__ W,
    const float* __restrict__ bias, float* __restrict__ outf,
    u16* __restrict__ outb, int M, int N, int K, int mode,
    u16* __restrict__ qb, u16* __restrict__ kb, u16* __restrict__ vb) {
  constexpr int TJ = BN / 32;            // B frag tiles per wave
  constexpr int NLD = 4 + TJ;            // gl_lds instructions per stage per wave
  constexpr int BSZ = (128 + BN) * GBK;  // u16 per buffer (A then B)
  __shared__ u16 SMEM[DEPTH * BSZ];
  int tid = threadIdx.x;
  int lane = tid & 63;
  int w = tid >> 6;                      // 0..3
  int lin = blockIdx.y * 64 + blockIdx.x;
  int xcd = lin & 7, slot = lin >> 3;
  int jj = slot % GY;
  int mm = (slot / GY) * 8 + xcd;
  int m0 = mm * 128;
  int j0 = jj * BN;
  int wrow = (w >> 1) * 64;
  int wcol = (w & 1) * (BN / 2);
  int lm = lane & 15;
  int kq = lane >> 4;
  int sw = lm & 7;
  int r8 = lane >> 3;
  int csrc = ((lane & 7) ^ r8) << 3;

  f32x4 acc[4][TJ];
#pragma unroll
  for (int i = 0; i < 4; i++)
#pragma unroll
    for (int j = 0; j < TJ; j++) acc[i][j] = (f32x4){0.f, 0.f, 0.f, 0.f};

  const u16* Ab = A + (size_t)m0 * K;
  const u16* Wb = W + (size_t)j0 * K;

  size_t soff[4];
#pragma unroll
  for (int u = 0; u < 4; u++)
    soff[u] = (size_t)(u * 32 + w * 8 + r8) * K + csrc;

  if constexpr (DEPTH == 2) {
    u16* As0 = SMEM;
    u16* Bs0 = SMEM + 2 * 128 * GBK;
    auto stage = [&](int kt, int pbb) {
#pragma unroll
      for (int u = 0; u < 4; u++)
        gl_lds16(&Ab[soff[u] + kt], &As0[pbb * 128 * GBK + (u * 4 + w) * 512]);
#pragma unroll
      for (int u = 0; u < TJ; u++)
        gl_lds16(&Wb[soff[u] + kt], &Bs0[pbb * BN * GBK + (u * 4 + w) * 512]);
    };
    stage(0, 0);
    int pb = 0;
    for (int kt = 0; kt < K; kt += GBK) {
      __syncthreads();                   // buf[pb] ready; buf[pb^1] reads done
      if (kt + GBK < K) stage(kt + GBK, pb ^ 1);
#pragma unroll
      for (int k2 = 0; k2 < GBK; k2 += 32) {
        int cc = ((((k2 >> 3) + kq) ^ sw) << 3);
        bf16x8 af[4], bfr[TJ];
#pragma unroll
        for (int t = 0; t < 4; t++)
          af[t] = *(const bf16x8*)&As0[pb * 128 * GBK + (wrow + t * 16 + lm) * GBK + cc];
#pragma unroll
        for (int tj = 0; tj < TJ; tj++)
          bfr[tj] = *(const bf16x8*)&Bs0[pb * BN * GBK + (wcol + tj * 16 + lm) * GBK + cc];
#pragma unroll
        for (int ti = 0; ti < 4; ti++)
#pragma unroll
          for (int tj = 0; tj < TJ; tj++)
            acc[ti][tj] = __builtin_amdgcn_mfma_f32_16x16x32_bf16(
                af[ti], bfr[tj], acc[ti][tj], 0, 0, 0);
      }
      pb ^= 1;
    }
  } else {
    // tri-buffer, counted-vmcnt pipeline (HW-validated round 9)
    auto stage3 = [&](int kt, int b) {
      u16* base = &SMEM[b * BSZ];
#pragma unroll
      for (int u = 0; u < 4; u++)
        gl_lds16(&Ab[soff[u] + kt], &base[(u * 4 + w) * 512]);
#pragma unroll
      for (int u = 0; u < TJ; u++)
        gl_lds16(&Wb[soff[u] + kt], &base[128 * GBK + (u * 4 + w) * 512]);
    };
    const int T = K / GBK;               // >= 3 for all our shapes
    stage3(0, 0);
    stage3(GBK, 1);
    int cur = 0;
    for (int t = 0; t < T; ++t) {
      if (t + 1 < T) {
        asm volatile("s_waitcnt vmcnt(%0)" :: "n"(NLD) : "memory");
      } else {
        asm volatile("s_waitcnt vmcnt(0)" ::: "memory");
      }
      __builtin_amdgcn_s_barrier();
      if (t + 2 < T) {
        int nb = cur + 2; if (nb >= 3) nb -= 3;
        stage3((t + 2) * GBK, nb);
      }
      const u16* As = &SMEM[cur * BSZ];
      const u16* Bs = &SMEM[cur * BSZ + 128 * GBK];
#pragma unroll
      for (int k2 = 0; k2 < GBK; k2 += 32) {
        int cc = ((((k2 >> 3) + kq) ^ sw) << 3);
        bf16x8 af[4], bfr[TJ];
#pragma unroll
        for (int t2 = 0; t2 < 4; t2++)
          af[t2] = *(const bf16x8*)&As[(wrow + t2 * 16 + lm) * GBK + cc];
#pragma unroll
        for (int tj = 0; tj < TJ; tj++)
          bfr[tj] = *(const bf16x8*)&Bs[(wcol + tj * 16 + lm) * GBK + cc];
#pragma unroll
        for (int ti = 0; ti < 4; ti++)
#pragma unroll
          for (int tj = 0; tj < TJ; tj++)
            acc[ti][tj] = __builtin_amdgcn_mfma_f32_16x16x32_bf16(
                af[ti], bfr[tj], acc[ti][tj], 0, 0, 0);
      }
      cur = (cur == 2) ? 0 : cur + 1;
    }
  }

  __syncthreads();                       // K-loop LDS reads done; SMEM reusable
  // C/D layout: col=lane&15, row=(lane>>4)*4+reg
  if (mode == 0) {
    float* Cf = (float*)SMEM;
    constexpr int CF = BN + 4;           // bank-shifted fp32 stride
#pragma unroll
    for (int p = 0; p < 2; p++) {        // two 64-row passes (LDS capacity)
      if ((w >> 1) == p) {
#pragma unroll
        for (int tj = 0; tj < TJ; tj++) {
          float bv = bias[j0 + wcol + tj * 16 + lm];
#pragma unroll
          for (int ti = 0; ti < 4; ti++)
#pragma unroll
            for (int r = 0; r < 4; r++)
              Cf[(ti * 16 + kq * 4 + r) * CF + wcol + tj * 16 + lm] =
                  acc[ti][tj][r] + bv;
        }
      }
      __syncthreads();
      constexpr int RC4 = BN / 4;        // float4 chunks per row
#pragma unroll
      for (int it = 0; it < 64 * RC4 / 256; it++) {
        int id = it * 256 + tid;
        int row = id / RC4, c4 = (id % RC4) * 4;
        float4 vq = *(float4*)&Cf[row * CF + c4];
        *(float4*)&outf[(size_t)(m0 + p * 64 + row) * N + j0 + c4] = vq;
      }
      __syncthreads();
    }
  } else {
    u16* Cs = (u16*)SMEM;
    constexpr int CS = BN + 8;           // bank-shifted u16 stride (16B-aligned rows)
#pragma unroll
    for (int tj = 0; tj < TJ; tj++) {
      int colj = j0 + wcol + tj * 16 + lm;
      float bv = bias[colj];
      float qs = (mode == 2 && colj < 512) ? 0.125f : 1.f;
#pragma unroll
      for (int ti = 0; ti < 4; ti++)
#pragma unroll
        for (int r = 0; r < 4; r++) {
          float val = acc[ti][tj][r] + bv;
          if (mode == 1) val = fmaxf(val, 0.f);
          Cs[(wrow + ti * 16 + kq * 4 + r) * CS + wcol + tj * 16 + lm] =
              f2bf(val * qs);
        }
    }
    __syncthreads();
    constexpr int RC8 = BN / 8;          // 16B chunks per row
#pragma unroll
    for (int it = 0; it < 128 * RC8 / 256; it++) {
      int id = it * 256 + tid;
      int row = id / RC8, c8 = (id % RC8) * 8;
      uint4 vq = *(uint4*)&Cs[row * CS + c8];
      if (mode == 1) {
        *(uint4*)&outb[(size_t)(m0 + row) * N + j0 + c8] = vq;
      } else {
        int col = j0 + c8;               // per-column split
        int which = col >> 9;
        int e = col & 511;
        int h = e >> 6, d0 = e & 63;
        int m = m0 + row, s = m >> 2, b = m & 3;
        u16* dst = (which == 0) ? qb : (which == 1) ? kb : vb;
        *(uint4*)&dst[((size_t)(b * H_NUM + h) * S_LEN + s) * HD + d0] = vq;
      }
    }
  }
}

// ---------------------------------------------------------------------------
// GBK=32 GEMM variant (FF1): 128x128 tile, 32KB LDS -> 4-5 blocks/CU (2-2.5x
// occupancy of the GBK=64 path) to hide the per-step barrier drain via
// cross-block overlap (m114 mechanism). Same proven 2-buffer __syncthreads
// loop. Addressing: 64B LDS rows (4 chunks of 16B); global source chunk
// pre-swizzled cg = c ^ (r&3) ^ ((r>>2)&3), linear LDS dest, read back at
// chunk kq ^ swz2 (same involution -> correct; bank-spread verified 2-way).
// mode-1 (relu->bf16) only; epilogue in two 64-row passes (Cs 17.4KB < 32KB).
// ---------------------------------------------------------------------------
__global__ __launch_bounds__(256) void mfma_gemm32(
    const u16* __restrict__ A, const u16* __restrict__ W,
    const float* __restrict__ bias, u16* __restrict__ outb,
    int M, int N, int K) {
  __shared__ u16 SMEM[2 * 8192];         // 2 bufs x (A 4096 + B 4096) u16
  int tid = threadIdx.x, lane = tid & 63, w = tid >> 6;
  int lin = blockIdx.y * 64 + blockIdx.x;
  int xcd = lin & 7, slot = lin >> 3;
  int jj = slot % 16;                    // GY=16 (N=2048 / 128)
  int mm = (slot / 16) * 8 + xcd;
  int m0 = mm * 128, j0 = jj * 128;
  int wrow = (w >> 1) * 64, wcol = (w & 1) * 64;
  int lm = lane & 15, kq = lane >> 4;
  int swz2 = (lm & 3) ^ ((lm >> 2) & 3);

  f32x4 acc[4][4];
#pragma unroll
  for (int i = 0; i < 4; i++)
#pragma unroll
    for (int j = 0; j < 4; j++) acc[i][j] = (f32x4){0.f, 0.f, 0.f, 0.f};

  const u16* Ab = A + (size_t)m0 * K;
  const u16* Wb = W + (size_t)j0 * K;

  // thread t stages chunks {t, t+256} of each operand; chunk q: row=q>>2, c=q&3.
  // +64 rows leaves (r&3) and ((r>>2)&3) unchanged -> same cg for both chunks.
  int rowA = tid >> 2, cA = tid & 3;
  int cgA = cA ^ ((rowA & 3) ^ ((rowA >> 2) & 3));
  size_t gA = (size_t)rowA * K + cgA * 8;
  size_t gA2 = gA + (size_t)64 * K;

  auto stage = [&](int kt, int pb) {
    gl_lds16(&Ab[gA + kt],  &SMEM[pb * 8192 + w * 512]);
    gl_lds16(&Ab[gA2 + kt], &SMEM[pb * 8192 + 2048 + w * 512]);
    gl_lds16(&Wb[gA + kt],  &SMEM[pb * 8192 + 4096 + w * 512]);
    gl_lds16(&Wb[gA2 + kt], &SMEM[pb * 8192 + 4096 + 2048 + w * 512]);
  };

  stage(0, 0);
  int pb = 0;
  for (int kt = 0; kt < K; kt += 32) {
    __syncthreads();                     // buf[pb] ready; buf[pb^1] reads done
    if (kt + 32 < K) stage(kt + 32, pb ^ 1);
    int ck = (kq ^ swz2) << 3;
    bf16x8 af[4], bfr[4];
#pragma unroll
    for (int t = 0; t < 4; t++)
      af[t] = *(const bf16x8*)&SMEM[pb * 8192 + ((wrow + t * 16 + lm) << 5) + ck];
#pragma unroll
    for (int tj = 0; tj < 4; tj++)
      bfr[tj] = *(const bf16x8*)&SMEM[pb * 8192 + 4096 + ((wcol + tj * 16 + lm) << 5) + ck];
#pragma unroll
    for (int ti = 0; ti < 4; ti++)
#pragma unroll
      for (int tj = 0; tj < 4; tj++)
        acc[ti][tj] = __builtin_amdgcn_mfma_f32_16x16x32_bf16(
            af[ti], bfr[tj], acc[ti][tj], 0, 0, 0);
    pb ^= 1;
  }

  // epilogue: relu+bias -> bf16, two 64-row passes through LDS
  __syncthreads();
  u16* Cs = SMEM;
  const int CS = 136;                    // 128 + 8, 16B-aligned rows
#pragma unroll
  for (int p = 0; p < 2; p++) {
    if ((w >> 1) == p) {
#pragma unroll
      for (int tj = 0; tj < 4; tj++) {
        float bv = bias[j0 + wcol + tj * 16 + lm];
#pragma unroll
        for (int ti = 0; ti < 4; ti++)
#pragma unroll
          for (int r = 0; r < 4; r++) {
            float val = fmaxf(acc[ti][tj][r] + bv, 0.f);
            Cs[(ti * 16 + kq * 4 + r) * CS + wcol + tj * 16 + lm] = f2bf(val);
          }
      }
    }
    __syncthreads();
#pragma unroll
    for (int it = 0; it < 4; it++) {     // 64 rows x 16 chunks = 1024 / 256
      int id = it * 256 + tid;
      int row = id >> 4, c8 = (id & 15) * 8;
      uint4 vq = *(uint4*)&Cs[row * CS + c8];
      *(uint4*)&outb[(size_t)(m0 + p * 64 + row) * N + j0 + c8] = vq;
    }
    __syncthreads();
  }
}

// ---------------------------------------------------------------------------
// V transpose: vb [bh][s][d] -> vt [bh][d][s] (unchanged)
// ---------------------------------------------------------------------------
__global__ __launch_bounds__(256) void vtrans_kernel(
    const u16* __restrict__ vb, u16* __restrict__ vt) {
  __shared__ u16 T[64 * 72];
  int tid = threadIdx.x;
  int bh = blockIdx.y, sc = blockIdx.x;
  const u16* src = vb + ((size_t)bh * S_LEN + sc * 64) * HD;
#pragma unroll
  for (int it = 0; it < 2; it++) {
    int id = it * 256 + tid;
    int srow = id >> 3, d8 = (id & 7) * 8;
    ushort4 v0 = *(const ushort4*)&src[srow * HD + d8];
    ushort4 v1 = *(const ushort4*)&src[srow * HD + d8 + 4];
    u16 arr[8] = {v0.x, v0.y, v0.z, v0.w, v1.x, v1.y, v1.z, v1.w};
#pragma unroll
    for (int j = 0; j < 8; j++) {
      int d = d8 + j;
      int rs = srow ^ (((d >> 3) & 7) << 3);   // swizzle 8-row blocks by d-group
      T[d * 72 + rs] = arr[j];
    }
  }
  __syncthreads();
#pragma unroll
  for (int it = 0; it < 2; it++) {
    int id = it * 256 + tid;
    int d = id >> 3, s8 = (id & 7) * 8;
    int blk = (s8 >> 3) ^ ((d >> 3) & 7);
    uint4 vq = *(uint4*)&T[d * 72 + (blk << 3)];
    *(uint4*)&vt[((size_t)bh * HD + d) * S_LEN + sc * 64 + s8] = vq;
  }
}

// ---------------------------------------------------------------------------
// MFMA attention v8 (unchanged)
// ---------------------------------------------------------------------------
__global__ __launch_bounds__(256) void attn_mfma_kernel(
    const u16* __restrict__ q, const u16* __restrict__ k,
    const u16* __restrict__ vt, u16* __restrict__ yb) {
  __shared__ u16 Ks[2 * 4096];  // [buf][c][d] swizzled
  __shared__ u16 Vs[2 * 4096];  // [buf][d][c] swizzled (from vt)
  __shared__ u16 Ps[4096];      // [q][c] XOR-granule swizzle, stride 64
  int tid = threadIdx.x, lane = tid & 63, w = tid >> 6;
  int quad = lane >> 4, lm = lane & 15;
  int sw = lm & 7;
  int r8 = lane >> 3;
  int csrc = ((lane & 7) ^ r8) << 3;
  int lin = blockIdx.y * 32 + blockIdx.x;
  int xcd = lin & 7, slot = lin >> 3;
  int bh = xcd * 4 + (slot >> 5);
  int i0 = (slot & 31) * 64;
  int b = bh >> 3, h = bh & 7;
  const u16* qp = q + ((size_t)bh * S_LEN + i0) * HD;
  const u16* kp = k + (size_t)bh * S_LEN * HD;
  const u16* vp = vt + (size_t)bh * HD * S_LEN;   // [d][s]

  // Q B-frag: lane needs Q[q=w*16+lm][quad*8 + k2 + j]
  bf16x8 qreg[2];
  {
    const u16* qr = qp + (size_t)(w * 16 + lm) * HD + quad * 8;
    qreg[0] = *(const bf16x8*)&qr[0];
    qreg[1] = *(const bf16x8*)&qr[32];
  }
  int psrow = (w * 16 + lm) * 64;
  int pshalf = (quad & 1) << 2;
  int psgq = quad >> 1;

  int cl = i0 - WIN; if (cl < 0) cl = 0;
  int chi = i0 + 63 + WIN; if (chi > S_LEN - 1) chi = S_LEN - 1;
  int nch = (chi - cl + 64) >> 6;      // local chunks exactly cover [cl, chi]
  int tlo = (cl + 255) >> 8;
  int thi0 = (chi >> 8) + 1;
  int ng = tlo + 8 - thi0;             // 6..7 global columns

  auto stage_local = [&](int ch, int pbuf) {
    int c0 = cl + (ch << 6);
#pragma unroll
    for (int u = 0; u < 2; u++) {
      int seg = u * 4 + w;
      int r = seg * 8 + r8;
      gl_lds16(&kp[(size_t)(c0 + r) * HD + csrc], &Ks[pbuf * 4096 + seg * 512]);
      gl_lds16(&vp[(size_t)r * S_LEN + c0 + csrc], &Vs[pbuf * 4096 + seg * 512]);
    }
  };
  auto stage_global = [&](int pbuf) {
    if (w == 0) {
      int rr = lane >> 3;
      int grow = (rr < tlo) ? (rr << 8) : ((thi0 + rr - tlo) << 8);
      if (rr >= ng) grow = 0;
      gl_lds16(&kp[(size_t)grow * HD + (((lane & 7) ^ rr) << 3)], &Ks[pbuf * 4096]);
    }
    for (int e = tid; e < 64 * 8; e += 256) {
      int d = e & 63, cg = e >> 6;
      if (cg < ng) {
        int gs = (cg < tlo) ? (cg << 8) : ((thi0 + cg - tlo) << 8);
        Vs[pbuf * 4096 + d * 64 + ((d & 7) << 3) + cg] = vp[(size_t)d * S_LEN + gs];
      }
    }
  };

  float m_i = -INFINITY, l_i = 0.f;     // per-lane scalars (own q = w*16+lm)
  f32x4 o[4];                           // o[tj][r] = O^T[d=tj*16+quad*4+r][q]
#pragma unroll
  for (int tj = 0; tj < 4; tj++) o[tj] = (f32x4){0.f, 0.f, 0.f, 0.f};

  stage_local(0, 0);
  __syncthreads();                      // buf0 ready (vmcnt drained by barrier)
  int pb = 0;
  for (int ch = 0; ch < nch; ch++) {
    // prefetch next chunk (or the global tail) into the other buffer
    if (ch + 1 < nch) stage_local(ch + 1, pb ^ 1);
    else stage_global(pb ^ 1);

    // QK^T swapped: s[tj][r] = S^T[c=tj*16+quad*4+r][q=w*16+lm]; maskless —
    // local chunks always lie fully inside the union window
    f32x4 s[4];
#pragma unroll
    for (int tj = 0; tj < 4; tj++) s[tj] = (f32x4){0.f, 0.f, 0.f, 0.f};
    __builtin_amdgcn_s_setprio(1);
#pragma unroll
    for (int hh = 0; hh < 2; hh++) {
      int cb = (hh << 2) + quad;
      bf16x8 qf = qreg[hh];
#pragma unroll
      for (int tj = 0; tj < 4; tj++) {
        bf16x8 kf = *(const bf16x8*)&Ks[pb * 4096 + (tj * 16 + lm) * 64 + ((cb ^ sw) << 3)];
        s[tj] = __builtin_amdgcn_mfma_f32_16x16x32_bf16(kf, qf, s[tj], 0, 0, 0);
      }
    }
    __builtin_amdgcn_s_setprio(0);
    // per-lane softmax over 16 regs + cross-quad (xor16, xor32)
    float mx = fmaxf(
        fmaxf(fmaxf(fmaxf(s[0][0], s[0][1]), fmaxf(s[0][2], s[0][3])),
              fmaxf(fmaxf(s[1][0], s[1][1]), fmaxf(s[1][2], s[1][3]))),
        fmaxf(fmaxf(fmaxf(s[2][0], s[2][1]), fmaxf(s[2][2], s[2][3])),
              fmaxf(fmaxf(s[3][0], s[3][1]), fmaxf(s[3][2], s[3][3]))));
    mx = fmaxf(mx, __shfl_xor(mx, 16));
    mx = fmaxf(mx, __shfl_xor(mx, 32));
    float mnew = fmaxf(m_i, mx);
    float al = __expf(m_i - mnew);
    float rs = 0.f;
#pragma unroll
    for (int tj = 0; tj < 4; tj++)
#pragma unroll
      for (int r = 0; r < 4; r++) {
        float p = __expf(s[tj][r] - mnew);
        s[tj][r] = p; rs += p;
      }
    rs += __shfl_xor(rs, 16);
    rs += __shfl_xor(rs, 32);
    l_i = l_i * al + rs;
    m_i = mnew;
#pragma unroll
    for (int tj = 0; tj < 4; tj++) {
      o[tj][0] *= al; o[tj][1] *= al; o[tj][2] *= al; o[tj][3] *= al;
    }
    // pack P (4 consecutive c per lane) -> 1 ds_write_b64 per tj
#pragma unroll
    for (int tj = 0; tj < 4; tj++) {
      uint2 up;
      up.x = cvtpk(s[tj][0], s[tj][1]);
      up.y = cvtpk(s[tj][2], s[tj][3]);
      *(uint2*)&Ps[psrow + ((((tj * 2 + psgq) ^ sw) << 3) | pshalf)] = up;
    }
    // PV swapped: o[tj] += mfma(V^T-frag(d rows), P-frag(q rows)) -> O^T
    __builtin_amdgcn_s_setprio(1);
#pragma unroll
    for (int hh = 0; hh < 2; hh++) {
      int cb = (hh << 2) + quad;
      bf16x8 pf = *(const bf16x8*)&Ps[psrow + ((cb ^ sw) << 3)];
#pragma unroll
      for (int tj = 0; tj < 4; tj++) {
        bf16x8 vf = *(const bf16x8*)&Vs[pb * 4096 + (tj * 16 + lm) * 64 + ((cb ^ sw) << 3)];
        o[tj] = __builtin_amdgcn_mfma_f32_16x16x32_bf16(vf, pf, o[tj], 0, 0, 0);
      }
    }
    __builtin_amdgcn_s_setprio(0);
    __syncthreads();   // drains prefetch vmcnt + all waves done reading buf pb
    pb ^= 1;
  }

  // ---- specialized global-column tail (ng cols, staged in Ks/Vs[pb]) ----
  {
    f32x4 s0 = (f32x4){0.f, 0.f, 0.f, 0.f};
#pragma unroll
    for (int hh = 0; hh < 2; hh++) {
      int cb = (hh << 2) + quad;
      bf16x8 kf = *(const bf16x8*)&Ks[pb * 4096 + lm * 64 + ((cb ^ sw) << 3)];
      s0 = __builtin_amdgcn_mfma_f32_16x16x32_bf16(kf, qreg[hh], s0, 0, 0, 0);
    }
#pragma unroll
    for (int r = 0; r < 4; r++)
      if (quad * 4 + r >= ng) s0[r] = -INFINITY;
    // online-softmax update over tile-0 only (tiles 1..3 are all -inf -> 0)
    float mx = fmaxf(fmaxf(s0[0], s0[1]), fmaxf(s0[2], s0[3]));
    mx = fmaxf(mx, __shfl_xor(mx, 16));
    mx = fmaxf(mx, __shfl_xor(mx, 32));
    float mnew = fmaxf(m_i, mx);
    float al = __expf(m_i - mnew);
    float rs = 0.f;
#pragma unroll
    for (int r = 0; r < 4; r++) { float p = __expf(s0[r] - mnew); s0[r] = p; rs += p; }
    rs += __shfl_xor(rs, 16);
    rs += __shfl_xor(rs, 32);
    l_i = l_i * al + rs;
    m_i = mnew;
#pragma unroll
    for (int tj = 0; tj < 4; tj++) {
      o[tj][0] *= al; o[tj][1] *= al; o[tj][2] *= al; o[tj][3] *= al;
    }
    // store tile-0 P; zero tile-1 granules so pf sees 0 for c in [16,32)
    uint2 up;
    up.x = cvtpk(s0[0], s0[1]);
    up.y = cvtpk(s0[2], s0[3]);
    *(uint2*)&Ps[psrow + (((psgq ^ sw) << 3) | pshalf)] = up;
    *(uint2*)&Ps[psrow + ((((2 + psgq) ^ sw) << 3) | pshalf)] = (uint2){0u, 0u};
    // PV: single k-step (c in [0,32)); P=0 beyond ng kills stale-V terms
    bf16x8 pf = *(const bf16x8*)&Ps[psrow + ((quad ^ sw) << 3)];
#pragma unroll
    for (int tj = 0; tj < 4; tj++) {
      bf16x8 vf = *(const bf16x8*)&Vs[pb * 4096 + (tj * 16 + lm) * 64 + ((quad ^ sw) << 3)];
      o[tj] = __builtin_amdgcn_mfma_f32_16x16x32_bf16(vf, pf, o[tj], 0, 0, 0);
    }
  }

  // epilogue: O^T -> Ps as [q][d] (packed b64 writes) -> 16B row stores
  float inv = 1.f / l_i;
#pragma unroll
  for (int tj = 0; tj < 4; tj++) {
    uint2 up;
    up.x = cvtpk(o[tj][0] * inv, o[tj][1] * inv);
    up.y = cvtpk(o[tj][2] * inv, o[tj][3] * inv);
    *(uint2*)&Ps[psrow + ((((tj * 2 + psgq) ^ sw) << 3) | pshalf)] = up;
  }
  __syncthreads();
#pragma unroll
  for (int it = 0; it < 2; it++) {
    int id = it * 256 + tid;
    int row = id >> 3, c8 = (id & 7) * 8;
    int blk = (id & 7) ^ (row & 7);
    uint4 vq = *(uint4*)&Ps[row * 64 + (blk << 3)];
    *(uint4*)&yb[((size_t)(i0 + row) * B_SZ + b) * E_DIM + h * HD + c8] = vq;
  }
}

// ---------------------------------------------------------------------------
// residual add + LayerNorm; optional bf16 secondary output
// ---------------------------------------------------------------------------
__global__ __launch_bounds__(256) void add_ln_kernel(
    const float* __restrict__ a, const float* __restrict__ r,
    const float* __restrict__ g, const float* __restrict__ be,
    float* __restrict__ out, u16* __restrict__ outb) {
  int wave = threadIdx.x >> 6;
  int lane = threadIdx.x & 63;
  int row = blockIdx.x * 4 + wave;
  const float* ar = a + (size_t)row * E_DIM;
  const float* rr = r + (size_t)row * E_DIM;
  float vals[8];
  float s = 0.f;
#pragma unroll
  for (int t = 0; t < 8; t++) {
    vals[t] = ar[t * 64 + lane] + rr[t * 64 + lane];
    s += vals[t];
  }
#pragma unroll
  for (int o = 32; o >= 1; o >>= 1) s += __shfl_xor(s, o, 64);
  float mu = s * (1.f / E_DIM);
  float vs = 0.f;
#pragma unroll
  for (int t = 0; t < 8; t++) { float d = vals[t] - mu; vs += d * d; }
#pragma unroll
  for (int o = 32; o >= 1; o >>= 1) vs += __shfl_xor(vs, o, 64);
  float inv = rsqrtf(vs * (1.f / E_DIM) + 1e-5f);
  float* orow = out + (size_t)row * E_DIM;
  u16* obrow = outb ? outb + (size_t)row * E_DIM : nullptr;
#pragma unroll
  for (int t = 0; t < 8; t++) {
    int e = t * 64 + lane;
    float val = (vals[t] - mu) * inv * g[e] + be[e];
    orow[e] = val;
    if (obrow) obrow[e] = f2bf(val);
  }
}

// ---------------------------------------------------------------------------
// launch
// ---------------------------------------------------------------------------
extern "C" void kernel_launch(void* const* d_in, const int* in_sizes, int n_in,
                              void* d_out, int out_size, void* d_ws, size_t ws_size,
                              hipStream_t stream) {
  const float* x     = (const float*)d_in[0];
  const float* pos   = (const float*)d_in[1];
  const float* in_w  = (const float*)d_in[2];
  const float* in_b  = (const float*)d_in[3];
  const float* out_w = (const float*)d_in[4];
  const float* out_b = (const float*)d_in[5];
  const float* w1    = (const float*)d_in[6];
  const float* b1    = (const float*)d_in[7];
  const float* w2    = (const float*)d_in[8];
  const float* b2    = (const float*)d_in[9];
  const float* g1    = (const float*)d_in[10];
  const float* be1   = (const float*)d_in[11];
  const float* g2    = (const float*)d_in[12];
  const float* be2   = (const float*)d_in[13];
  float* out = (float*)d_out;

  char* base = (char*)d_ws;
  float* xp    = (float*)(base);
  u16*   xpb   = (u16*)(base + ((size_t)16 << 20));
  u16*   qb    = (u16*)(base + ((size_t)24 << 20));
  u16*   kb    = (u16*)(base + ((size_t)32 << 20));
  u16*   vb    = (u16*)(base + ((size_t)40 << 20));
  u16*   ybf   = (u16*)(base + ((size_t)48 << 20));
  float* aprj  = (float*)(base + ((size_t)56 << 20));
  u16*   vt    = (u16*)(base + ((size_t)56 << 20));  // overlaps aprj: vt dead
                                                     // before out-proj writes aprj
  u16*   inwb  = (u16*)(base + ((size_t)72 << 20));
  u16*   outwb = (u16*)(base + ((size_t)74 << 20));
  u16*   w1b   = (u16*)(base + ((size_t)76 << 20));
  u16*   w2b   = (u16*)(base + ((size_t)78 << 20));
  float* x1    = xp;
  u16*   x1b   = xpb;
  u16*   ff1b  = qb;      // 24M..56M
  float* ff2   = aprj;

  prep_kernel<<<7168, 256, 0, stream>>>(x, pos, xp, xpb,
                                        in_w, out_w, w1, w2, inwb, outwb, w1b, w2b);
  // QKV: verified best geometry (R5)
  mfma_gemm<128, 12, 2><<<dim3(64, 12), 256, 0, stream>>>(xpb, inwb, in_b, nullptr, nullptr,
                                                          NROWS, 1536, 512, 2, qb, kb, vb);
  vtrans_kernel<<<dim3(32, 32), 256, 0, stream>>>(vb, vt);
  attn_mfma_kernel<<<dim3(32, 32), 256, 0, stream>>>(qb, kb, vt, ybf);
  // out-proj + FF2: tri-buffer counted-vmcnt (HW-validated round 9)
  mfma_gemm<64, 8, 3><<<dim3(64, 8), 256, 0, stream>>>(ybf, outwb, out_b, aprj, nullptr,
                                                       NROWS, 512, 512, 0, nullptr, nullptr, nullptr);
  add_ln_kernel<<<2048, 256, 0, stream>>>(xp, aprj, g1, be1, x1, x1b);
  // FF1: GBK=32 high-occupancy variant (this round's single experiment)
  mfma_gemm32<<<dim3(64, 16), 256, 0, stream>>>(x1b, w1b, b1, ff1b,
                                                NROWS, 2048, 512);
  mfma_gemm<64, 8, 3><<<dim3(64, 8), 256, 0, stream>>>(ff1b, w2b, b2, ff2, nullptr,
                                                       NROWS, 512, 2048, 0, nullptr, nullptr, nullptr);
  add_ln_kernel<<<2048, 256, 0, stream>>>(x1, ff2, g2, be2, out, nullptr);
}

// Round 13
// 225.686 us; speedup vs baseline: 1.0569x; 1.0569x over previous
//
#include <hip/hip_runtime.h>
#include <hip/hip_bf16.h>
#include <math.h>

#define S_LEN 2048
#define B_SZ  4
#define E_DIM 512
#define H_NUM 8
#define HD    64
#define FF_DIM 2048
#define NROWS 8192
#define WIN   128

typedef unsigned short u16;
typedef __bf16 bf16x8 __attribute__((ext_vector_type(8)));
typedef float  f32x4  __attribute__((ext_vector_type(4)));

// fp32 -> bf16 round-to-nearest-even
__device__ __forceinline__ u16 f2bf(float f) {
  union { float f; unsigned u; } v; v.f = f;
  unsigned u = v.u;
  return (u16)((u + 0x7fffu + ((u >> 16) & 1u)) >> 16);
}

// pack two f32 -> u32 of 2 bf16 (RNE), single VALU op
__device__ __forceinline__ unsigned cvtpk(float lo, float hi) {
  unsigned r;
  asm("v_cvt_pk_bf16_f32 %0, %1, %2" : "=v"(r) : "v"(lo), "v"(hi));
  return r;
}

// async global->LDS, 16B per lane; LDS dest = wave-uniform base + lane*16
__device__ __forceinline__ void gl_lds16(const u16* gp, u16* lp) {
  __builtin_amdgcn_global_load_lds(
      (const __attribute__((address_space(1))) unsigned int*)gp,
      (__attribute__((address_space(3))) unsigned int*)lp, 16, 0, 0);
}

// ---------------------------------------------------------------------------
// merged prep: x+pos -> bf16 only (fp32 x+pos is recomputed in add_pos_ln,
// saving a 16MB HBM write), and 4-matrix weight cast.
// GRID MUST BE 7168 blocks: 1048576 (x+pos) + 786432 (weights) threads.
// ---------------------------------------------------------------------------
__global__ __launch_bounds__(256) void prep_kernel(
    const float* __restrict__ x, const float* __restrict__ pos,
    u16* __restrict__ xpb,
    const float* __restrict__ s0, const float* __restrict__ s1,
    const float* __restrict__ s2, const float* __restrict__ s3,
    u16* __restrict__ d0, u16* __restrict__ d1,
    u16* __restrict__ d2, u16* __restrict__ d3) {
  int i = blockIdx.x * blockDim.x + threadIdx.x;
  if (i < 1048576) {
    float4 xv = ((const float4*)x)[i];
    float4 pv = ((const float4*)pos)[i & 511];
    ushort4 ob;
    ob.x = f2bf(xv.x + pv.x); ob.y = f2bf(xv.y + pv.y);
    ob.z = f2bf(xv.z + pv.z); ob.w = f2bf(xv.w + pv.w);
    ((ushort4*)xpb)[i] = ob;
  } else {
    int j = i - 1048576;
    const int n0 = 196608, n1 = 65536, n2 = 262144;
    const float4* sp; ushort4* dp; int off;
    if (j < n0)                { sp = (const float4*)s0; dp = (ushort4*)d0; off = j; }
    else if (j < n0 + n1)      { sp = (const float4*)s1; dp = (ushort4*)d1; off = j - n0; }
    else if (j < n0 + n1 + n2) { sp = (const float4*)s2; dp = (ushort4*)d2; off = j - n0 - n1; }
    else                       { sp = (const float4*)s3; dp = (ushort4*)d3; off = j - n0 - n1 - n2; }
    float4 v = sp[off];
    ushort4 o; o.x = f2bf(v.x); o.y = f2bf(v.y); o.z = f2bf(v.z); o.w = f2bf(v.w);
    dp[off] = o;
  }
}

// ---------------------------------------------------------------------------
// bf16 MFMA GEMM (R10-verified; DEPTH=2 and DEPTH=3 paths unchanged)
// ---------------------------------------------------------------------------
#define GBK 64

template <int BN, int GY, int DEPTH>
__global__ __launch_bounds__(256) void mfma_gemm(
    const u16* __restrict__ A, const u16* __restrict__ W,
    const float* __restrict__ bias, float* __restrict__ outf,
    u16* __restrict__ outb, int M, int N, int K, int mode,
    u16* __restrict__ qb, u16* __restrict__ kb, u16* __restrict__ vb) {
  constexpr int TJ = BN / 32;            // B frag tiles per wave
  constexpr int NLD = 4 + TJ;            // gl_lds instructions per stage per wave
  constexpr int BSZ = (128 + BN) * GBK;  // u16 per buffer (A then B)
  __shared__ u16 SMEM[DEPTH * BSZ];
  int tid = threadIdx.x;
  int lane = tid & 63;
  int w = tid >> 6;                      // 0..3
  int lin = blockIdx.y * 64 + blockIdx.x;
  int xcd = lin & 7, slot = lin >> 3;
  int jj = slot % GY;
  int mm = (slot / GY) * 8 + xcd;
  int m0 = mm * 128;
  int j0 = jj * BN;
  int wrow = (w >> 1) * 64;
  int wcol = (w & 1) * (BN / 2);
  int lm = lane & 15;
  int kq = lane >> 4;
  int sw = lm & 7;
  int r8 = lane >> 3;
  int csrc = ((lane & 7) ^ r8) << 3;

  f32x4 acc[4][TJ];
#pragma unroll
  for (int i = 0; i < 4; i++)
#pragma unroll
    for (int j = 0; j < TJ; j++) acc[i][j] = (f32x4){0.f, 0.f, 0.f, 0.f};

  const u16* Ab = A + (size_t)m0 * K;
  const u16* Wb = W + (size_t)j0 * K;

  size_t soff[4];
#pragma unroll
  for (int u = 0; u < 4; u++)
    soff[u] = (size_t)(u * 32 + w * 8 + r8) * K + csrc;

  if constexpr (DEPTH == 2) {
    u16* As0 = SMEM;
    u16* Bs0 = SMEM + 2 * 128 * GBK;
    auto stage = [&](int kt, int pbb) {
#pragma unroll
      for (int u = 0; u < 4; u++)
        gl_lds16(&Ab[soff[u] + kt], &As0[pbb * 128 * GBK + (u * 4 + w) * 512]);
#pragma unroll
      for (int u = 0; u < TJ; u++)
        gl_lds16(&Wb[soff[u] + kt], &Bs0[pbb * BN * GBK + (u * 4 + w) * 512]);
    };
    stage(0, 0);
    int pb = 0;
    for (int kt = 0; kt < K; kt += GBK) {
      __syncthreads();                   // buf[pb] ready; buf[pb^1] reads done
      if (kt + GBK < K) stage(kt + GBK, pb ^ 1);
#pragma unroll
      for (int k2 = 0; k2 < GBK; k2 += 32) {
        int cc = ((((k2 >> 3) + kq) ^ sw) << 3);
        bf16x8 af[4], bfr[TJ];
#pragma unroll
        for (int t = 0; t < 4; t++)
          af[t] = *(const bf16x8*)&As0[pb * 128 * GBK + (wrow + t * 16 + lm) * GBK + cc];
#pragma unroll
        for (int tj = 0; tj < TJ; tj++)
          bfr[tj] = *(const bf16x8*)&Bs0[pb * BN * GBK + (wcol + tj * 16 + lm) * GBK + cc];
#pragma unroll
        for (int ti = 0; ti < 4; ti++)
#pragma unroll
          for (int tj = 0; tj < TJ; tj++)
            acc[ti][tj] = __builtin_amdgcn_mfma_f32_16x16x32_bf16(
                af[ti], bfr[tj], acc[ti][tj], 0, 0, 0);
      }
      pb ^= 1;
    }
  } else {
    // tri-buffer, counted-vmcnt pipeline (HW-validated round 9)
    auto stage3 = [&](int kt, int b) {
      u16* base = &SMEM[b * BSZ];
#pragma unroll
      for (int u = 0; u < 4; u++)
        gl_lds16(&Ab[soff[u] + kt], &base[(u * 4 + w) * 512]);
#pragma unroll
      for (int u = 0; u < TJ; u++)
        gl_lds16(&Wb[soff[u] + kt], &base[128 * GBK + (u * 4 + w) * 512]);
    };
    const int T = K / GBK;               // >= 3 for all our shapes
    stage3(0, 0);
    stage3(GBK, 1);
    int cur = 0;
    for (int t = 0; t < T; ++t) {
      if (t + 1 < T) {
        asm volatile("s_waitcnt vmcnt(%0)" :: "n"(NLD) : "memory");
      } else {
        asm volatile("s_waitcnt vmcnt(0)" ::: "memory");
      }
      __builtin_amdgcn_s_barrier();
      if (t + 2 < T) {
        int nb = cur + 2; if (nb >= 3) nb -= 3;
        stage3((t + 2) * GBK, nb);
      }
      const u16* As = &SMEM[cur * BSZ];
      const u16* Bs = &SMEM[cur * BSZ + 128 * GBK];
#pragma unroll
      for (int k2 = 0; k2 < GBK; k2 += 32) {
        int cc = ((((k2 >> 3) + kq) ^ sw) << 3);
        bf16x8 af[4], bfr[TJ];
#pragma unroll
        for (int t2 = 0; t2 < 4; t2++)
          af[t2] = *(const bf16x8*)&As[(wrow + t2 * 16 + lm) * GBK + cc];
#pragma unroll
        for (int tj = 0; tj < TJ; tj++)
          bfr[tj] = *(const bf16x8*)&Bs[(wcol + tj * 16 + lm) * GBK + cc];
#pragma unroll
        for (int ti = 0; ti < 4; ti++)
#pragma unroll
          for (int tj = 0; tj < TJ; tj++)
            acc[ti][tj] = __builtin_amdgcn_mfma_f32_16x16x32_bf16(
                af[ti], bfr[tj], acc[ti][tj], 0, 0, 0);
      }
      cur = (cur == 2) ? 0 : cur + 1;
    }
  }

  __syncthreads();                       // K-loop LDS reads done; SMEM reusable
  // C/D layout: col=lane&15, row=(lane>>4)*4+reg
  if (mode == 0) {
    float* Cf = (float*)SMEM;
    constexpr int CF = BN + 4;           // bank-shifted fp32 stride
#pragma unroll
    for (int p = 0; p < 2; p++) {        // two 64-row passes (LDS capacity)
      if ((w >> 1) == p) {
#pragma unroll
        for (int tj = 0; tj < TJ; tj++) {
          float bv = bias[j0 + wcol + tj * 16 + lm];
#pragma unroll
          for (int ti = 0; ti < 4; ti++)
#pragma unroll
            for (int r = 0; r < 4; r++)
              Cf[(ti * 16 + kq * 4 + r) * CF + wcol + tj * 16 + lm] =
                  acc[ti][tj][r] + bv;
        }
      }
      __syncthreads();
      constexpr int RC4 = BN / 4;        // float4 chunks per row
#pragma unroll
      for (int it = 0; it < 64 * RC4 / 256; it++) {
        int id = it * 256 + tid;
        int row = id / RC4, c4 = (id % RC4) * 4;
        float4 vq = *(float4*)&Cf[row * CF + c4];
        *(float4*)&outf[(size_t)(m0 + p * 64 + row) * N + j0 + c4] = vq;
      }
      __syncthreads();
    }
  } else {
    u16* Cs = (u16*)SMEM;
    constexpr int CS = BN + 8;           // bank-shifted u16 stride (16B-aligned rows)
#pragma unroll
    for (int tj = 0; tj < TJ; tj++) {
      int colj = j0 + wcol + tj * 16 + lm;
      float bv = bias[colj];
      float qs = (mode == 2 && colj < 512) ? 0.125f : 1.f;
#pragma unroll
      for (int ti = 0; ti < 4; ti++)
#pragma unroll
        for (int r = 0; r < 4; r++) {
          float val = acc[ti][tj][r] + bv;
          if (mode == 1) val = fmaxf(val, 0.f);
          Cs[(wrow + ti * 16 + kq * 4 + r) * CS + wcol + tj * 16 + lm] =
              f2bf(val * qs);
        }
    }
    __syncthreads();
    constexpr int RC8 = BN / 8;          // 16B chunks per row
#pragma unroll
    for (int it = 0; it < 128 * RC8 / 256; it++) {
      int id = it * 256 + tid;
      int row = id / RC8, c8 = (id % RC8) * 8;
      uint4 vq = *(uint4*)&Cs[row * CS + c8];
      if (mode == 1) {
        *(uint4*)&outb[(size_t)(m0 + row) * N + j0 + c8] = vq;
      } else {
        int col = j0 + c8;               // per-column split
        int which = col >> 9;
        int e = col & 511;
        int h = e >> 6, d0 = e & 63;
        int m = m0 + row, s = m >> 2, b = m & 3;
        u16* dst = (which == 0) ? qb : (which == 1) ? kb : vb;
        *(uint4*)&dst[((size_t)(b * H_NUM + h) * S_LEN + s) * HD + d0] = vq;
      }
    }
  }
}

// ---------------------------------------------------------------------------
// V transpose: vb [bh][s][d] -> vt [bh][d][s] (unchanged)
// ---------------------------------------------------------------------------
__global__ __launch_bounds__(256) void vtrans_kernel(
    const u16* __restrict__ vb, u16* __restrict__ vt) {
  __shared__ u16 T[64 * 72];
  int tid = threadIdx.x;
  int bh = blockIdx.y, sc = blockIdx.x;
  const u16* src = vb + ((size_t)bh * S_LEN + sc * 64) * HD;
#pragma unroll
  for (int it = 0; it < 2; it++) {
    int id = it * 256 + tid;
    int srow = id >> 3, d8 = (id & 7) * 8;
    ushort4 v0 = *(const ushort4*)&src[srow * HD + d8];
    ushort4 v1 = *(const ushort4*)&src[srow * HD + d8 + 4];
    u16 arr[8] = {v0.x, v0.y, v0.z, v0.w, v1.x, v1.y, v1.z, v1.w};
#pragma unroll
    for (int j = 0; j < 8; j++) {
      int d = d8 + j;
      int rs = srow ^ (((d >> 3) & 7) << 3);   // swizzle 8-row blocks by d-group
      T[d * 72 + rs] = arr[j];
    }
  }
  __syncthreads();
#pragma unroll
  for (int it = 0; it < 2; it++) {
    int id = it * 256 + tid;
    int d = id >> 3, s8 = (id & 7) * 8;
    int blk = (s8 >> 3) ^ ((d >> 3) & 7);
    uint4 vq = *(uint4*)&T[d * 72 + (blk << 3)];
    *(uint4*)&vt[((size_t)bh * HD + d) * S_LEN + sc * 64 + s8] = vq;
  }
}

// ---------------------------------------------------------------------------
// MFMA attention v8 (unchanged)
// ---------------------------------------------------------------------------
__global__ __launch_bounds__(256) void attn_mfma_kernel(
    const u16* __restrict__ q, const u16* __restrict__ k,
    const u16* __restrict__ vt, u16* __restrict__ yb) {
  __shared__ u16 Ks[2 * 4096];  // [buf][c][d] swizzled
  __shared__ u16 Vs[2 * 4096];  // [buf][d][c] swizzled (from vt)
  __shared__ u16 Ps[4096];      // [q][c] XOR-granule swizzle, stride 64
  int tid = threadIdx.x, lane = tid & 63, w = tid >> 6;
  int quad = lane >> 4, lm = lane & 15;
  int sw = lm & 7;
  int r8 = lane >> 3;
  int csrc = ((lane & 7) ^ r8) << 3;
  int lin = blockIdx.y * 32 + blockIdx.x;
  int xcd = lin & 7, slot = lin >> 3;
  int bh = xcd * 4 + (slot >> 5);
  int i0 = (slot & 31) * 64;
  int b = bh >> 3, h = bh & 7;
  const u16* qp = q + ((size_t)bh * S_LEN + i0) * HD;
  const u16* kp = k + (size_t)bh * S_LEN * HD;
  const u16* vp = vt + (size_t)bh * HD * S_LEN;   // [d][s]

  // Q B-frag: lane needs Q[q=w*16+lm][quad*8 + k2 + j]
  bf16x8 qreg[2];
  {
    const u16* qr = qp + (size_t)(w * 16 + lm) * HD + quad * 8;
    qreg[0] = *(const bf16x8*)&qr[0];
    qreg[1] = *(const bf16x8*)&qr[32];
  }
  int psrow = (w * 16 + lm) * 64;
  int pshalf = (quad & 1) << 2;
  int psgq = quad >> 1;

  int cl = i0 - WIN; if (cl < 0) cl = 0;
  int chi = i0 + 63 + WIN; if (chi > S_LEN - 1) chi = S_LEN - 1;
  int nch = (chi - cl + 64) >> 6;      // local chunks exactly cover [cl, chi]
  int tlo = (cl + 255) >> 8;
  int thi0 = (chi >> 8) + 1;
  int ng = tlo + 8 - thi0;             // 6..7 global columns

  auto stage_local = [&](int ch, int pbuf) {
    int c0 = cl + (ch << 6);
#pragma unroll
    for (int u = 0; u < 2; u++) {
      int seg = u * 4 + w;
      int r = seg * 8 + r8;
      gl_lds16(&kp[(size_t)(c0 + r) * HD + csrc], &Ks[pbuf * 4096 + seg * 512]);
      gl_lds16(&vp[(size_t)r * S_LEN + c0 + csrc], &Vs[pbuf * 4096 + seg * 512]);
    }
  };
  auto stage_global = [&](int pbuf) {
    if (w == 0) {
      int rr = lane >> 3;
      int grow = (rr < tlo) ? (rr << 8) : ((thi0 + rr - tlo) << 8);
      if (rr >= ng) grow = 0;
      gl_lds16(&kp[(size_t)grow * HD + (((lane & 7) ^ rr) << 3)], &Ks[pbuf * 4096]);
    }
    for (int e = tid; e < 64 * 8; e += 256) {
      int d = e & 63, cg = e >> 6;
      if (cg < ng) {
        int gs = (cg < tlo) ? (cg << 8) : ((thi0 + cg - tlo) << 8);
        Vs[pbuf * 4096 + d * 64 + ((d & 7) << 3) + cg] = vp[(size_t)d * S_LEN + gs];
      }
    }
  };

  float m_i = -INFINITY, l_i = 0.f;     // per-lane scalars (own q = w*16+lm)
  f32x4 o[4];                           // o[tj][r] = O^T[d=tj*16+quad*4+r][q]
#pragma unroll
  for (int tj = 0; tj < 4; tj++) o[tj] = (f32x4){0.f, 0.f, 0.f, 0.f};

  stage_local(0, 0);
  __syncthreads();                      // buf0 ready (vmcnt drained by barrier)
  int pb = 0;
  for (int ch = 0; ch < nch; ch++) {
    // prefetch next chunk (or the global tail) into the other buffer
    if (ch + 1 < nch) stage_local(ch + 1, pb ^ 1);
    else stage_global(pb ^ 1);

    // QK^T swapped: s[tj][r] = S^T[c=tj*16+quad*4+r][q=w*16+lm]; maskless —
    // local chunks always lie fully inside the union window
    f32x4 s[4];
#pragma unroll
    for (int tj = 0; tj < 4; tj++) s[tj] = (f32x4){0.f, 0.f, 0.f, 0.f};
    __builtin_amdgcn_s_setprio(1);
#pragma unroll
    for (int hh = 0; hh < 2; hh++) {
      int cb = (hh << 2) + quad;
      bf16x8 qf = qreg[hh];
#pragma unroll
      for (int tj = 0; tj < 4; tj++) {
        bf16x8 kf = *(const bf16x8*)&Ks[pb * 4096 + (tj * 16 + lm) * 64 + ((cb ^ sw) << 3)];
        s[tj] = __builtin_amdgcn_mfma_f32_16x16x32_bf16(kf, qf, s[tj], 0, 0, 0);
      }
    }
    __builtin_amdgcn_s_setprio(0);
    // per-lane softmax over 16 regs + cross-quad (xor16, xor32)
    float mx = fmaxf(
        fmaxf(fmaxf(fmaxf(s[0][0], s[0][1]), fmaxf(s[0][2], s[0][3])),
              fmaxf(fmaxf(s[1][0], s[1][1]), fmaxf(s[1][2], s[1][3]))),
        fmaxf(fmaxf(fmaxf(s[2][0], s[2][1]), fmaxf(s[2][2], s[2][3])),
              fmaxf(fmaxf(s[3][0], s[3][1]), fmaxf(s[3][2], s[3][3]))));
    mx = fmaxf(mx, __shfl_xor(mx, 16));
    mx = fmaxf(mx, __shfl_xor(mx, 32));
    float mnew = fmaxf(m_i, mx);
    float al = __expf(m_i - mnew);
    float rs = 0.f;
#pragma unroll
    for (int tj = 0; tj < 4; tj++)
#pragma unroll
      for (int r = 0; r < 4; r++) {
        float p = __expf(s[tj][r] - mnew);
        s[tj][r] = p; rs += p;
      }
    rs += __shfl_xor(rs, 16);
    rs += __shfl_xor(rs, 32);
    l_i = l_i * al + rs;
    m_i = mnew;
#pragma unroll
    for (int tj = 0; tj < 4; tj++) {
      o[tj][0] *= al; o[tj][1] *= al; o[tj][2] *= al; o[tj][3] *= al;
    }
    // pack P (4 consecutive c per lane) -> 1 ds_write_b64 per tj
#pragma unroll
    for (int tj = 0; tj < 4; tj++) {
      uint2 up;
      up.x = cvtpk(s[tj][0], s[tj][1]);
      up.y = cvtpk(s[tj][2], s[tj][3]);
      *(uint2*)&Ps[psrow + ((((tj * 2 + psgq) ^ sw) << 3) | pshalf)] = up;
    }
    // PV swapped: o[tj] += mfma(V^T-frag(d rows), P-frag(q rows)) -> O^T
    __builtin_amdgcn_s_setprio(1);
#pragma unroll
    for (int hh = 0; hh < 2; hh++) {
      int cb = (hh << 2) + quad;
      bf16x8 pf = *(const bf16x8*)&Ps[psrow + ((cb ^ sw) << 3)];
#pragma unroll
      for (int tj = 0; tj < 4; tj++) {
        bf16x8 vf = *(const bf16x8*)&Vs[pb * 4096 + (tj * 16 + lm) * 64 + ((cb ^ sw) << 3)];
        o[tj] = __builtin_amdgcn_mfma_f32_16x16x32_bf16(vf, pf, o[tj], 0, 0, 0);
      }
    }
    __builtin_amdgcn_s_setprio(0);
    __syncthreads();   // drains prefetch vmcnt + all waves done reading buf pb
    pb ^= 1;
  }

  // ---- specialized global-column tail (ng cols, staged in Ks/Vs[pb]) ----
  {
    f32x4 s0 = (f32x4){0.f, 0.f, 0.f, 0.f};
#pragma unroll
    for (int hh = 0; hh < 2; hh++) {
      int cb = (hh << 2) + quad;
      bf16x8 kf = *(const bf16x8*)&Ks[pb * 4096 + lm * 64 + ((cb ^ sw) << 3)];
      s0 = __builtin_amdgcn_mfma_f32_16x16x32_bf16(kf, qreg[hh], s0, 0, 0, 0);
    }
#pragma unroll
    for (int r = 0; r < 4; r++)
      if (quad * 4 + r >= ng) s0[r] = -INFINITY;
    // online-softmax update over tile-0 only (tiles 1..3 are all -inf -> 0)
    float mx = fmaxf(fmaxf(s0[0], s0[1]), fmaxf(s0[2], s0[3]));
    mx = fmaxf(mx, __shfl_xor(mx, 16));
    mx = fmaxf(mx, __shfl_xor(mx, 32));
    float mnew = fmaxf(m_i, mx);
    float al = __expf(m_i - mnew);
    float rs = 0.f;
#pragma unroll
    for (int r = 0; r < 4; r++) { float p = __expf(s0[r] - mnew); s0[r] = p; rs += p; }
    rs += __shfl_xor(rs, 16);
    rs += __shfl_xor(rs, 32);
    l_i = l_i * al + rs;
    m_i = mnew;
#pragma unroll
    for (int tj = 0; tj < 4; tj++) {
      o[tj][0] *= al; o[tj][1] *= al; o[tj][2] *= al; o[tj][3] *= al;
    }
    // store tile-0 P; zero tile-1 granules so pf sees 0 for c in [16,32)
    uint2 up;
    up.x = cvtpk(s0[0], s0[1]);
    up.y = cvtpk(s0[2], s0[3]);
    *(uint2*)&Ps[psrow + (((psgq ^ sw) << 3) | pshalf)] = up;
    *(uint2*)&Ps[psrow + ((((2 + psgq) ^ sw) << 3) | pshalf)] = (uint2){0u, 0u};
    // PV: single k-step (c in [0,32)); P=0 beyond ng kills stale-V terms
    bf16x8 pf = *(const bf16x8*)&Ps[psrow + ((quad ^ sw) << 3)];
#pragma unroll
    for (int tj = 0; tj < 4; tj++) {
      bf16x8 vf = *(const bf16x8*)&Vs[pb * 4096 + (tj * 16 + lm) * 64 + ((quad ^ sw) << 3)];
      o[tj] = __builtin_amdgcn_mfma_f32_16x16x32_bf16(vf, pf, o[tj], 0, 0, 0);
    }
  }

  // epilogue: O^T -> Ps as [q][d] (packed b64 writes) -> 16B row stores
  float inv = 1.f / l_i;
#pragma unroll
  for (int tj = 0; tj < 4; tj++) {
    uint2 up;
    up.x = cvtpk(o[tj][0] * inv, o[tj][1] * inv);
    up.y = cvtpk(o[tj][2] * inv, o[tj][3] * inv);
    *(uint2*)&Ps[psrow + ((((tj * 2 + psgq) ^ sw) << 3) | pshalf)] = up;
  }
  __syncthreads();
#pragma unroll
  for (int it = 0; it < 2; it++) {
    int id = it * 256 + tid;
    int row = id >> 3, c8 = (id & 7) * 8;
    int blk = (id & 7) ^ (row & 7);
    uint4 vq = *(uint4*)&Ps[row * 64 + (blk << 3)];
    *(uint4*)&yb[((size_t)(i0 + row) * B_SZ + b) * E_DIM + h * HD + c8] = vq;
  }
}

// ---------------------------------------------------------------------------
// x + pos + attn_out, then LayerNorm (residual recomputed from x/pos:
// addition order (x+pos)+r matches the previous xp+r bit-exactly)
// ---------------------------------------------------------------------------
__global__ __launch_bounds__(256) void add_pos_ln_kernel(
    const float* __restrict__ x, const float* __restrict__ pos,
    const float* __restrict__ r,
    const float* __restrict__ g, const float* __restrict__ be,
    float* __restrict__ out, u16* __restrict__ outb) {
  int wave = threadIdx.x >> 6;
  int lane = threadIdx.x & 63;
  int row = blockIdx.x * 4 + wave;
  const float* xr = x + (size_t)row * E_DIM;
  const float* pr = pos + (size_t)(row & 3) * E_DIM;
  const float* rr = r + (size_t)row * E_DIM;
  float vals[8];
  float s = 0.f;
#pragma unroll
  for (int t = 0; t < 8; t++) {
    int e = t * 64 + lane;
    vals[t] = (xr[e] + pr[e]) + rr[e];
    s += vals[t];
  }
#pragma unroll
  for (int o = 32; o >= 1; o >>= 1) s += __shfl_xor(s, o, 64);
  float mu = s * (1.f / E_DIM);
  float vs = 0.f;
#pragma unroll
  for (int t = 0; t < 8; t++) { float d = vals[t] - mu; vs += d * d; }
#pragma unroll
  for (int o = 32; o >= 1; o >>= 1) vs += __shfl_xor(vs, o, 64);
  float inv = rsqrtf(vs * (1.f / E_DIM) + 1e-5f);
  float* orow = out + (size_t)row * E_DIM;
  u16* obrow = outb + (size_t)row * E_DIM;
#pragma unroll
  for (int t = 0; t < 8; t++) {
    int e = t * 64 + lane;
    float val = (vals[t] - mu) * inv * g[e] + be[e];
    orow[e] = val;
    obrow[e] = f2bf(val);
  }
}

// ---------------------------------------------------------------------------
// residual add + LayerNorm; optional bf16 secondary output
// ---------------------------------------------------------------------------
__global__ __launch_bounds__(256) void add_ln_kernel(
    const float* __restrict__ a, const float* __restrict__ r,
    const float* __restrict__ g, const float* __restrict__ be,
    float* __restrict__ out, u16* __restrict__ outb) {
  int wave = threadIdx.x >> 6;
  int lane = threadIdx.x & 63;
  int row = blockIdx.x * 4 + wave;
  const float* ar = a + (size_t)row * E_DIM;
  const float* rr = r + (size_t)row * E_DIM;
  float vals[8];
  float s = 0.f;
#pragma unroll
  for (int t = 0; t < 8; t++) {
    vals[t] = ar[t * 64 + lane] + rr[t * 64 + lane];
    s += vals[t];
  }
#pragma unroll
  for (int o = 32; o >= 1; o >>= 1) s += __shfl_xor(s, o, 64);
  float mu = s * (1.f / E_DIM);
  float vs = 0.f;
#pragma unroll
  for (int t = 0; t < 8; t++) { float d = vals[t] - mu; vs += d * d; }
#pragma unroll
  for (int o = 32; o >= 1; o >>= 1) vs += __shfl_xor(vs, o, 64);
  float inv = rsqrtf(vs * (1.f / E_DIM) + 1e-5f);
  float* orow = out + (size_t)row * E_DIM;
  u16* obrow = outb ? outb + (size_t)row * E_DIM : nullptr;
#pragma unroll
  for (int t = 0; t < 8; t++) {
    int e = t * 64 + lane;
    float val = (vals[t] - mu) * inv * g[e] + be[e];
    orow[e] = val;
    if (obrow) obrow[e] = f2bf(val);
  }
}

// ---------------------------------------------------------------------------
// launch
// ---------------------------------------------------------------------------
extern "C" void kernel_launch(void* const* d_in, const int* in_sizes, int n_in,
                              void* d_out, int out_size, void* d_ws, size_t ws_size,
                              hipStream_t stream) {
  const float* x     = (const float*)d_in[0];
  const float* pos   = (const float*)d_in[1];
  const float* in_w  = (const float*)d_in[2];
  const float* in_b  = (const float*)d_in[3];
  const float* out_w = (const float*)d_in[4];
  const float* out_b = (const float*)d_in[5];
  const float* w1    = (const float*)d_in[6];
  const float* b1    = (const float*)d_in[7];
  const float* w2    = (const float*)d_in[8];
  const float* b2    = (const float*)d_in[9];
  const float* g1    = (const float*)d_in[10];
  const float* be1   = (const float*)d_in[11];
  const float* g2    = (const float*)d_in[12];
  const float* be2   = (const float*)d_in[13];
  float* out = (float*)d_out;

  char* base = (char*)d_ws;
  float* x1    = (float*)(base);                     // LN1 output (fp32)
  u16*   xpb   = (u16*)(base + ((size_t)16 << 20));  // bf16 x+pos
  u16*   qb    = (u16*)(base + ((size_t)24 << 20));
  u16*   kb    = (u16*)(base + ((size_t)32 << 20));
  u16*   vb    = (u16*)(base + ((size_t)40 << 20));
  u16*   ybf   = (u16*)(base + ((size_t)48 << 20));
  float* aprj  = (float*)(base + ((size_t)56 << 20));
  u16*   vt    = (u16*)(base + ((size_t)56 << 20));  // overlaps aprj: vt dead
                                                     // before out-proj writes aprj
  u16*   inwb  = (u16*)(base + ((size_t)72 << 20));
  u16*   outwb = (u16*)(base + ((size_t)74 << 20));
  u16*   w1b   = (u16*)(base + ((size_t)76 << 20));
  u16*   w2b   = (u16*)(base + ((size_t)78 << 20));
  u16*   x1b   = xpb;     // LN1 bf16 output reuses xpb (dead after QKV)
  u16*   ff1b  = qb;      // 24M..56M
  float* ff2   = aprj;

  // 7168 blocks: 1048576 x+pos threads + 786432 weight-cast threads
  prep_kernel<<<7168, 256, 0, stream>>>(x, pos, xpb,
                                        in_w, out_w, w1, w2, inwb, outwb, w1b, w2b);
  // QKV: verified best geometry (R5)
  mfma_gemm<128, 12, 2><<<dim3(64, 12), 256, 0, stream>>>(xpb, inwb, in_b, nullptr, nullptr,
                                                          NROWS, 1536, 512, 2, qb, kb, vb);
  vtrans_kernel<<<dim3(32, 32), 256, 0, stream>>>(vb, vt);
  attn_mfma_kernel<<<dim3(32, 32), 256, 0, stream>>>(qb, kb, vt, ybf);
  // out-proj + FF2: tri-buffer counted-vmcnt (HW-validated round 9)
  mfma_gemm<64, 8, 3><<<dim3(64, 8), 256, 0, stream>>>(ybf, outwb, out_b, aprj, nullptr,
                                                       NROWS, 512, 512, 0, nullptr, nullptr, nullptr);
  add_pos_ln_kernel<<<2048, 256, 0, stream>>>(x, pos, aprj, g1, be1, x1, x1b);
  // FF1: verified best geometry (R5)
  mfma_gemm<128, 16, 2><<<dim3(64, 16), 256, 0, stream>>>(x1b, w1b, b1, nullptr, ff1b,
                                                          NROWS, 2048, 512, 1, nullptr, nullptr, nullptr);
  mfma_gemm<64, 8, 3><<<dim3(64, 8), 256, 0, stream>>>(ff1b, w2b, b2, ff2, nullptr,
                                                       NROWS, 512, 2048, 0, nullptr, nullptr, nullptr);
  add_ln_kernel<<<2048, 256, 0, stream>>>(x1, ff2, g2, be2, out, nullptr);
}